// Round 14
// baseline (216.222 us; speedup 1.0000x reference)
//
#include <hip/hip_runtime.h>
#include <hip/hip_bf16.h>

typedef float f32x4 __attribute__((ext_vector_type(4)));
typedef short s16x8 __attribute__((ext_vector_type(8)));
typedef unsigned short u16;

#define B_ 2
#define S_ 2048
#define HID 1536
#define NQ_ 24
#define NKV_ 4
#define HD 64
#define NTOK (B_*S_)
#define QKVN ((NQ_+2*NKV_)*HD)   // 2048

// fused setup kernel job split
#define CVT_BLKS  ((QKVN*HID + HID*HID)/4/256)   // 5376
#define RMS_BLKS  NTOK                            // 4096
#define TAB_BLKS  (S_*32/256)                     // 256
#define SETUP_BLKS (CVT_BLKS + RMS_BLKS + TAB_BLKS)

#define ROPE2_BLOCKS ((NTOK*28*16)/256)  // 7168 (2 rot-pairs per thread)
#define VT_BLOCKS (B_*NKV_*(S_/64))      // 256

// Compiler-only memory fence (single-wave block: LDS pipe is in-order, no s_barrier
// needed -> avoids the vmcnt(0) drain). Proven R6->R7 on k_attn.
#define LDS_FENCE() asm volatile("" ::: "memory")

// Counted-vmcnt barrier pair (T4): wait for all but the newest N loads, then raw
// s_barrier -- deliberately does NOT drain the in-flight prefetch.
#define WAITBAR(n) asm volatile("s_waitcnt vmcnt(" #n ")\n\ts_barrier" ::: "memory")
#define RAWBAR()   asm volatile("s_barrier" ::: "memory")

__device__ __forceinline__ float bf2f(u16 u) {
  unsigned int x = ((unsigned int)u) << 16;
  float f; __builtin_memcpy(&f, &x, 4); return f;
}
__device__ __forceinline__ u16 f2bf(float f) {
  unsigned int u; __builtin_memcpy(&u, &f, 4);
  u += 0x7fffu + ((u >> 16) & 1u);
  return (u16)(u >> 16);
}
// 4x f32 -> packed bf16x4 via v_cvt_pk_bf16_f32
__device__ __forceinline__ unsigned long long pk4bf(float a, float b, float c, float d) {
  __hip_bfloat162 x = __float22bfloat162_rn(make_float2(a, b));
  __hip_bfloat162 y = __float22bfloat162_rn(make_float2(c, d));
  unsigned int xi, yi;
  __builtin_memcpy(&xi, &x, 4);
  __builtin_memcpy(&yi, &y, 4);
  return (unsigned long long)xi | ((unsigned long long)yi << 32);
}

// ---------------- fused setup: weight cvt + RMSNorm + RoPE cos/sin table ----------------
// R16 (verified +6us): one launch, block-range-split jobs. Table lives in d_out's
// buffer (dead until GEMM2 writes it).
__global__ __launch_bounds__(256) void k_setup(const float* __restrict__ x,
                                               const float* __restrict__ g,
                                               const float* __restrict__ wq,
                                               const float* __restrict__ wo,
                                               u16* __restrict__ wb,
                                               u16* __restrict__ xn,
                                               float2* __restrict__ tab,
                                               const int* __restrict__ spp) {
  int bid = blockIdx.x, tid = threadIdx.x;
  if (bid < CVT_BLKS) {
    int i = bid * 256 + tid;   // quad index
    const int n0q = QKVN*HID/4;
    const float* src = (i < n0q) ? wq : wo;
    int j = (i < n0q) ? i : i - n0q;
    f32x4 v = ((const f32x4*)src)[j];
    *(unsigned long long*)(wb + (size_t)i*4) = pk4bf(v[0], v[1], v[2], v[3]);
  } else if (bid < CVT_BLKS + RMS_BLKS) {
    int row = bid - CVT_BLKS;
    const f32x4* xr = (const f32x4*)(x + (size_t)row * HID);
    f32x4 v0 = {}, v1 = {};
    float ss = 0.f;
    if (tid < 192) {
      v0 = xr[2*tid]; v1 = xr[2*tid + 1];
      ss = v0[0]*v0[0] + v0[1]*v0[1] + v0[2]*v0[2] + v0[3]*v0[3]
         + v1[0]*v1[0] + v1[1]*v1[1] + v1[2]*v1[2] + v1[3]*v1[3];
    }
#pragma unroll
    for (int off = 1; off < 64; off <<= 1) ss += __shfl_xor(ss, off);
    __shared__ float red[4];
    if ((tid & 63) == 0) red[tid >> 6] = ss;
    __syncthreads();
    float rs = rsqrtf((red[0] + red[1] + red[2] + red[3]) * (1.f/HID) + 1e-6f);
    if (tid < 192) {
      const f32x4* gr = (const f32x4*)g;
      f32x4 g0 = gr[2*tid], g1 = gr[2*tid + 1];
      unsigned long long* out = (unsigned long long*)(xn + (size_t)row * HID);
      out[2*tid]     = pk4bf(v0[0]*rs*g0[0], v0[1]*rs*g0[1], v0[2]*rs*g0[2], v0[3]*rs*g0[3]);
      out[2*tid + 1] = pk4bf(v1[0]*rs*g1[0], v1[1]*rs*g1[1], v1[2]*rs*g1[2], v1[3]*rs*g1[3]);
    }
  } else {
    int i = (bid - CVT_BLKS - RMS_BLKS) * 256 + tid;   // [0, 65536)
    int s = i >> 5, p = i & 31;
    float t = (float)(spp[0] + s);
    // 10000^(-p/32) = exp2(-p*log2(1e4)/32)
    float inv = exp2f((float)p * -0.41524101186f);
    float sn, cs;
    sincosf(t * inv, &sn, &cs);
    tab[i] = make_float2(cs, sn);
  }
}

// ---------------- GEMM C[M][N] = A[M][K] @ W[N][K]^T, M fixed = 4096 ----------------
// R17: BK 64 -> 32. At BK=64 the 48KB LDS capped residency at 3 blocks/CU, so
// GEMM1's 1024 blocks couldn't all co-reside (R15: +1 block/CU ~ +10%). BK=32 ->
// 24KB LDS + __launch_bounds__(256,4) (VGPR cap 128 >= the 116 in use -> no spill)
// -> 4 blocks/CU, GEMM1 fully resident. Counted vmcnt(3) (3 loads/stage), XOR
// slot-swizzle over the 4 16B-slots of each 64B row, XCD M-stripe kept.
template <bool F32OUT>
__global__ __launch_bounds__(256, 4) void k_gemm_bt(const u16* __restrict__ A,
                                                    const u16* __restrict__ W,
                                                    void* __restrict__ Cv,
                                                    const float* __restrict__ resid,
                                                    int N, int K) {
  __shared__ __align__(16) u16 As0[128*32], Bs0[64*32];
  __shared__ __align__(16) u16 As1[128*32], Bs1[64*32];
  int lin = blockIdx.x;
  int xcd = lin & 7, loc = lin >> 3;
  int mloc = loc & 3, nloc = loc >> 2;          // stripe height 4 (32 Mtiles / 8 XCDs)
  int m0 = (xcd*4 + mloc) * 128, n0 = nloc * 64;
  int tid = threadIdx.x;
  int w = tid >> 6, l = tid & 63;
  int wr = w >> 1, wc = w & 1;
  int c = l & 15, g = l >> 4;
  f32x4 acc[4][2] = {};
  // Staging: one gload = 64 lanes x 16B = 1KB = 16 rows x 64B. Lane l: row l>>2,
  // 16B-slot l&3. Source slot pre-swizzled: physical slot (l&3) holds logical
  // slot (l&3)^(row&3) (rule 21: swizzle source + read, LDS dest stays linear).
  int r16 = l >> 2;
  int sslot = (l & 3) ^ (r16 & 3);
  const u16* Ag = A + (size_t)(m0 + w*32 + r16)*K + sslot*8;   // 2 loads: rows w*32+i*16
  const u16* Wg = W + (size_t)(n0 + w*16 + r16)*K + sslot*8;   // 1 load: rows w*16

#define STAGE(dA, dB, k0) do {                                                          \
  _Pragma("unroll")                                                                     \
  for (int i = 0; i < 2; i++)                                                           \
    __builtin_amdgcn_global_load_lds(                                                   \
        (const __attribute__((address_space(1))) void*)(Ag + (size_t)(i*16)*K + (k0)),  \
        (__attribute__((address_space(3))) void*)(dA + (w*32 + i*16)*32), 16, 0, 0);    \
  __builtin_amdgcn_global_load_lds(                                                     \
      (const __attribute__((address_space(1))) void*)(Wg + (k0)),                       \
      (__attribute__((address_space(3))) void*)(dB + (w*16)*32), 16, 0, 0);             \
  } while (0)

  // Read: row r holds its logical slot j at physical j^(r&3); af needs logical
  // slot g of row (..+c) -> physical (g^(c&3)). 4-way bank alias (c,c+4,c+8,c+12)
  // costs 1.58x on ~6 ds_reads -- acceptable.
#define COMPUTE(sA, sB) do {                                                            \
    s16x8 af[4], bq[2];                                                                 \
    int sl = (g ^ (c & 3)) * 8;                                                         \
    _Pragma("unroll")                                                                   \
    for (int mt = 0; mt < 4; mt++)                                                      \
      af[mt] = *(const s16x8*)(sA + (wr*64 + mt*16 + c)*32 + sl);                       \
    _Pragma("unroll")                                                                   \
    for (int nt = 0; nt < 2; nt++)                                                      \
      bq[nt] = *(const s16x8*)(sB + (wc*32 + nt*16 + c)*32 + sl);                       \
    _Pragma("unroll")                                                                   \
    for (int mt = 0; mt < 4; mt++)                                                      \
      _Pragma("unroll")                                                                 \
      for (int nt = 0; nt < 2; nt++)                                                    \
        acc[mt][nt] = __builtin_amdgcn_mfma_f32_16x16x32_bf16(af[mt], bq[nt],           \
                                                              acc[mt][nt], 0, 0, 0);    \
  } while (0)

  const int NT = K >> 5;            // 48 K-tiles of 32 (even, >= 4)
  STAGE(As0, Bs0, 0);
  STAGE(As1, Bs1, 32);
  WAITBAR(3);                       // tile0 landed; tile1 in flight
  for (int t = 0; t + 2 < NT; t += 2) {
    COMPUTE(As0, Bs0);              // tile t (landed)
    RAWBAR();                       // all waves done reading As0/Bs0
    STAGE(As0, Bs0, (t+2)*32);
    WAITBAR(3);                     // tile t+1 landed; t+2 in flight
    COMPUTE(As1, Bs1);              // tile t+1
    RAWBAR();                       // all waves done reading As1/Bs1
    if (t + 3 < NT) {
      STAGE(As1, Bs1, (t+3)*32);
      WAITBAR(3);                   // tile t+2 landed; t+3 in flight
    } else {
      WAITBAR(0);
    }
  }
  COMPUTE(As0, Bs0);                // tile NT-2 (landed via last WAITBAR)
  WAITBAR(0);                       // tile NT-1 landed
  COMPUTE(As1, Bs1);                // tile NT-1
#undef STAGE
#undef COMPUTE

#pragma unroll
  for (int mt = 0; mt < 4; mt++)
#pragma unroll
    for (int nt = 0; nt < 2; nt++)
#pragma unroll
      for (int r = 0; r < 4; r++) {
        int m = m0 + wr*64 + mt*16 + g*4 + r;
        int n = n0 + wc*32 + nt*16 + c;
        size_t off = (size_t)m*N + n;
        float vv = acc[mt][nt][r];
        if (F32OUT) {
          ((float*)Cv)[off] = vv + resid[off];
        } else {
          ((u16*)Cv)[off] = f2bf(vv);
        }
      }
}

// ---------------- fused RoPE(q,k) + V transpose (one launch) ----------------
// R16 (verified): table-based rotation; each thread does TWO rotation pairs.
__global__ __launch_bounds__(256) void k_rope_vt(const u16* __restrict__ qkv,
                                                 u16* __restrict__ q,
                                                 u16* __restrict__ k,
                                                 u16* __restrict__ vt,
                                                 const float2* __restrict__ tab) {
  __shared__ u16 tile[64][65];
  int bid = blockIdx.x;
  if (bid < ROPE2_BLOCKS) {
    int idx = bid * 256 + threadIdx.x;     // (tok*28 + h)*16 + j ; j covers p=2j,2j+1
    int j = idx & 15;
    int h = (idx >> 4) % 28;
    int tok = idx / 448;
    int s = tok & (S_ - 1);
    int b = tok >> 11;
    f32x4 cs = *(const f32x4*)(tab + (size_t)s*32 + 2*j);   // c0,s0,c1,s1 (16B aligned)
    int col = (h < NQ_) ? h*64 + 4*j : HID + (h - NQ_)*64 + 4*j;
    unsigned long long pr = *(const unsigned long long*)(qkv + (size_t)tok*QKVN + col);
    float x1a = bf2f((u16)pr),         x2a = bf2f((u16)(pr >> 16));
    float x1b = bf2f((u16)(pr >> 32)), x2b = bf2f((u16)(pr >> 48));
    float ya1 = x1a*cs[0] - x2a*cs[1];
    float ya2 = x2a*cs[0] + x1a*cs[1];
    float yb1 = x1b*cs[2] - x2b*cs[3];
    float yb2 = x2b*cs[2] + x1b*cs[3];
    unsigned long long outp = pk4bf(ya1, ya2, yb1, yb2);
    if (h < NQ_) {
      *(unsigned long long*)(q + (((size_t)(b*NQ_ + h))*S_ + s)*64 + 4*j) = outp;
    } else {
      *(unsigned long long*)(k + (((size_t)(b*NKV_ + (h - NQ_)))*S_ + s)*64 + 4*j) = outp;
    }
  } else {
    int blk = bid - ROPE2_BLOCKS;
    int st = blk & 31;
    int hk = (blk >> 5) & 3;
    int b = blk >> 7;
    int s0 = st * 64;
#pragma unroll
    for (int i = 0; i < 16; i++) {
      int ii = threadIdx.x + i*256;
      int r = ii >> 6, cc = ii & 63;
      tile[r][cc] = qkv[((size_t)(b*S_) + s0 + r)*QKVN + (NQ_+NKV_)*64 + hk*64 + cc];
    }
    __syncthreads();
#pragma unroll
    for (int i = 0; i < 16; i++) {
      int ii = threadIdx.x + i*256;
      int d = ii >> 6, s = ii & 63;
      vt[((size_t)(b*NKV_ + hk)*64 + d)*S_ + s0 + s] = tile[s][d];
    }
  }
}

// ---------------- Flash attention, one wave per (b,h,32-query tile) ----------------
// R4-exact structure (proven 43.4us) + R17 defer-max (T13): skip the alpha-exp and
// o/l rescale when no query's max grew by >8 (wave-uniform ballot). P bounded by
// e^8 -- fine in bf16/f32. Removes ~34 VALU ops from the serial chain on most
// iterations (running max stabilizes after the first tiles).
__global__ __launch_bounds__(64, 3) void k_attn(const u16* __restrict__ q,
                                                const u16* __restrict__ k,
                                                const u16* __restrict__ vt,
                                                u16* __restrict__ ao,
                                                const int* __restrict__ spp) {
  __shared__ __align__(16) u16 Pt[32*72];
  int lin = blockIdx.x;
  int xcd = lin & 7, loc = lin >> 3;
  int qb = loc & 63;
  int bh = xcd * 6 + (loc >> 6);   // [0,48)
  int h = bh % NQ_;
  int b = bh / NQ_;
  int q0 = qb * 32;
  int hk = h / (NQ_/NKV_);
  int l = threadIdx.x;
  int c = l & 15, g = l >> 4;
  int sp = spp[0];
  const u16* qptr = q + ((size_t)(b*NQ_ + h))*S_*64;
  const u16* kptr = k + ((size_t)(b*NKV_ + hk))*S_*64;
  const u16* vptr = vt + ((size_t)(b*NKV_ + hk))*64*S_;

  s16x8 qf[2][2];
#pragma unroll
  for (int qt = 0; qt < 2; qt++)
#pragma unroll
    for (int ks = 0; ks < 2; ks++)
      qf[qt][ks] = *(const s16x8*)(qptr + (size_t)(q0 + qt*16 + c)*64 + ks*32 + g*8);

  f32x4 o[4][2] = {};          // o[dt][qt]: O^T accum, row=d col=q
  float m_run[2], l_run[2];
#pragma unroll
  for (int i = 0; i < 2; i++) { m_run[i] = -1e30f; l_run[i] = 0.f; }

  int lo = sp + q0 - 256; if (lo < 0) lo = 0;
  int hi = sp + q0 + 31;  if (hi > S_ - 1) hi = S_ - 1;
  int kt0 = lo >> 6, kt1 = hi >> 6;

  s16x8 kf[4][2];
#pragma unroll
  for (int km = 0; km < 4; km++)
#pragma unroll
    for (int ks = 0; ks < 2; ks++)
      kf[km][ks] = *(const s16x8*)(kptr + (size_t)(kt0*64 + km*16 + c)*64 + ks*32 + g*8);

  for (int kt = kt0; kt <= kt1; kt++) {
    s16x8 vf[2][4];
#pragma unroll
    for (int ks = 0; ks < 2; ks++)
#pragma unroll
      for (int dt = 0; dt < 4; dt++)
        vf[ks][dt] = *(const s16x8*)(vptr + (size_t)(dt*16 + c)*S_ + kt*64 + ks*32 + g*8);

    bool full = (kt*64 + 63 <= sp + q0) && (kt*64 >= sp + q0 - 225);
#pragma unroll
    for (int qt = 0; qt < 2; qt++) {
      f32x4 sa[4];               // S^T slice for this qt: row=key col=query
      __builtin_amdgcn_s_setprio(1);
#pragma unroll
      for (int km = 0; km < 4; km++) {
        f32x4 z = {};
        z = __builtin_amdgcn_mfma_f32_16x16x32_bf16(kf[km][0], qf[qt][0], z, 0, 0, 0);
        sa[km] = __builtin_amdgcn_mfma_f32_16x16x32_bf16(kf[km][1], qf[qt][1], z, 0, 0, 0);
      }
      __builtin_amdgcn_s_setprio(0);
      if (qt == 1 && kt < kt1) {
#pragma unroll
        for (int km = 0; km < 4; km++)
#pragma unroll
          for (int ks = 0; ks < 2; ks++)
            kf[km][ks] = *(const s16x8*)(kptr + (size_t)((kt+1)*64 + km*16 + c)*64 + ks*32 + g*8);
      }
      float mx = -1e30f;
      if (full) {
#pragma unroll
        for (int km = 0; km < 4; km++)
#pragma unroll
          for (int r = 0; r < 4; r++) {
            float sv = sa[km][r] * 0.125f;
            sa[km][r] = sv;
            mx = fmaxf(mx, sv);
          }
      } else {
        int pos = sp + q0 + qt*16 + c;
#pragma unroll
        for (int km = 0; km < 4; km++)
#pragma unroll
          for (int r = 0; r < 4; r++) {
            int key = kt*64 + km*16 + g*4 + r;
            float sv = sa[km][r] * 0.125f;
            sv = ((unsigned)(pos - key) <= 256u) ? sv : -1e30f;
            sa[km][r] = sv;
            mx = fmaxf(mx, sv);
          }
      }
      mx = fmaxf(mx, __shfl_xor(mx, 16));
      mx = fmaxf(mx, __shfl_xor(mx, 32));
      // T13 defer-max: only rescale when some query's max grew by >8.
      if (__ballot(mx > m_run[qt] + 8.f) != 0) {
        float mnew = fmaxf(m_run[qt], mx);
        float alpha = __expf(m_run[qt] - mnew);
        m_run[qt] = mnew;
        l_run[qt] *= alpha;
#pragma unroll
        for (int dt = 0; dt < 4; dt++) {
          o[dt][qt][0] *= alpha; o[dt][qt][1] *= alpha;
          o[dt][qt][2] *= alpha; o[dt][qt][3] *= alpha;
        }
      }
      float mref = m_run[qt];
      float rsum = 0.f;
#pragma unroll
      for (int km = 0; km < 4; km++) {
        float p0 = __expf(sa[km][0] - mref);   // masked -1e30 underflows to 0
        float p1 = __expf(sa[km][1] - mref);
        float p2 = __expf(sa[km][2] - mref);
        float p3 = __expf(sa[km][3] - mref);
        rsum += p0 + p1 + p2 + p3;
        *(unsigned long long*)(Pt + (qt*16 + c)*72 + km*16 + g*4) = pk4bf(p0, p1, p2, p3);
      }
      rsum += __shfl_xor(rsum, 16);
      rsum += __shfl_xor(rsum, 32);
      l_run[qt] += rsum;
    }
    LDS_FENCE();   // Pt writes ordered before reads (in-order DS pipe, same wave)
    // PV: O^T += V^T @ P^T
    __builtin_amdgcn_s_setprio(1);
#pragma unroll
    for (int ks = 0; ks < 2; ks++)
#pragma unroll
      for (int qt = 0; qt < 2; qt++) {
        s16x8 pf = *(const s16x8*)(Pt + (qt*16 + c)*72 + ks*32 + g*8);
#pragma unroll
        for (int dt = 0; dt < 4; dt++)
          o[dt][qt] = __builtin_amdgcn_mfma_f32_16x16x32_bf16(vf[ks][dt], pf, o[dt][qt], 0, 0, 0);
      }
    __builtin_amdgcn_s_setprio(0);
    LDS_FENCE();   // Pt reads ordered before next iteration's writes
  }
#pragma unroll
  for (int qt = 0; qt < 2; qt++) {
    float inv = 1.f / l_run[qt];
    int qi = q0 + qt*16 + c;
    u16* row = ao + ((size_t)(b*S_) + qi)*HID + h*64;
#pragma unroll
    for (int dt = 0; dt < 4; dt++)
      *(unsigned long long*)(row + dt*16 + g*4) =
          pk4bf(o[dt][qt][0]*inv, o[dt][qt][1]*inv, o[dt][qt][2]*inv, o[dt][qt][3]*inv);
  }
}

extern "C" void kernel_launch(void* const* d_in, const int* in_sizes, int n_in,
                              void* d_out, int out_size, void* d_ws, size_t ws_size,
                              hipStream_t stream) {
  const float* x_f32    = (const float*)d_in[0];
  const float* g_f32    = (const float*)d_in[1];
  const float* wqkv_f32 = (const float*)d_in[2];
  const float* wout_f32 = (const float*)d_in[3];
  const int*   spp      = (const int*)d_in[4];
  char* ws = (char*)d_ws;
  // workspace layout (bytes), ~57.1 MB total
  u16* wqkvb = (u16*)(ws);                    //  6,291,456
  u16* woutb = (u16*)(ws + 6291456);          //  4,718,592 (contiguous with wqkvb)
  u16* xn    = (u16*)(ws + 11010048);         // 12,582,912
  u16* qkv   = (u16*)(ws + 23592960);         // 16,777,216
  u16* qbuf  = (u16*)(ws + 40370176);         // 12,582,912
  u16* kbuf  = (u16*)(ws + 52953088);         //  2,097,152
  u16* vtb   = (u16*)(ws + 55050240);         //  2,097,152  (end 57,147,392)
  u16* attn  = xn;                            // aliases xn (dead after GEMM1)
  // RoPE table lives in d_out's buffer (512KB of 25MB; dead until GEMM2 writes it)
  float2* tab = (float2*)d_out;

  k_setup<<<SETUP_BLKS, 256, 0, stream>>>(x_f32, g_f32, wqkv_f32, wout_f32,
                                          wqkvb, xn, tab, spp);
  k_gemm_bt<false><<<32*(QKVN/64), 256, 0, stream>>>(xn, wqkvb, qkv, nullptr, QKVN, HID);
  k_rope_vt<<<ROPE2_BLOCKS + VT_BLOCKS, 256, 0, stream>>>(qkv, qbuf, kbuf, vtb,
                                                          (const float2*)tab);
  k_attn<<<B_*NQ_*(S_/32), 64, 0, stream>>>(qbuf, kbuf, vtb, attn, spp);
  k_gemm_bt<true><<<32*(HID/64), 256, 0, stream>>>(attn, woutb, d_out, x_f32, HID, HID);
}

// Round 15
// 202.877 us; speedup vs baseline: 1.0658x; 1.0658x over previous
//
#include <hip/hip_runtime.h>
#include <hip/hip_bf16.h>

typedef float f32x4 __attribute__((ext_vector_type(4)));
typedef short s16x8 __attribute__((ext_vector_type(8)));
typedef unsigned short u16;

#define B_ 2
#define S_ 2048
#define HID 1536
#define NQ_ 24
#define NKV_ 4
#define HD 64
#define NTOK (B_*S_)
#define QKVN ((NQ_+2*NKV_)*HD)   // 2048

// fused setup kernel job split
#define CVT_BLKS  ((QKVN*HID + HID*HID)/4/256)   // 5376
#define RMS_BLKS  NTOK                            // 4096
#define TAB_BLKS  (S_*32/256)                     // 256
#define SETUP_BLKS (CVT_BLKS + RMS_BLKS + TAB_BLKS)

#define ROPE2_BLOCKS ((NTOK*28*16)/256)  // 7168 (2 rot-pairs per thread)
#define VT_BLOCKS (B_*NKV_*(S_/64))      // 256

// Compiler-only memory fence (single-wave block: LDS pipe is in-order, no s_barrier
// needed -> avoids the vmcnt(0) drain). Proven R6->R7 on k_attn.
#define LDS_FENCE() asm volatile("" ::: "memory")

// Counted-vmcnt barrier pair (T4): wait for all but the newest N loads, then raw
// s_barrier -- deliberately does NOT drain the in-flight prefetch.
#define WAITBAR(n) asm volatile("s_waitcnt vmcnt(" #n ")\n\ts_barrier" ::: "memory")
#define RAWBAR()   asm volatile("s_barrier" ::: "memory")

__device__ __forceinline__ float bf2f(u16 u) {
  unsigned int x = ((unsigned int)u) << 16;
  float f; __builtin_memcpy(&f, &x, 4); return f;
}
__device__ __forceinline__ u16 f2bf(float f) {
  unsigned int u; __builtin_memcpy(&u, &f, 4);
  u += 0x7fffu + ((u >> 16) & 1u);
  return (u16)(u >> 16);
}
// 4x f32 -> packed bf16x4 via v_cvt_pk_bf16_f32
__device__ __forceinline__ unsigned long long pk4bf(float a, float b, float c, float d) {
  __hip_bfloat162 x = __float22bfloat162_rn(make_float2(a, b));
  __hip_bfloat162 y = __float22bfloat162_rn(make_float2(c, d));
  unsigned int xi, yi;
  __builtin_memcpy(&xi, &x, 4);
  __builtin_memcpy(&yi, &y, 4);
  return (unsigned long long)xi | ((unsigned long long)yi << 32);
}

// ---------------- fused setup: weight cvt + RMSNorm + RoPE cos/sin table ----------------
// R16 (verified +6us): one launch, block-range-split jobs. Table lives in d_out's
// buffer (dead until GEMM2 writes it).
__global__ __launch_bounds__(256) void k_setup(const float* __restrict__ x,
                                               const float* __restrict__ g,
                                               const float* __restrict__ wq,
                                               const float* __restrict__ wo,
                                               u16* __restrict__ wb,
                                               u16* __restrict__ xn,
                                               float2* __restrict__ tab,
                                               const int* __restrict__ spp) {
  int bid = blockIdx.x, tid = threadIdx.x;
  if (bid < CVT_BLKS) {
    int i = bid * 256 + tid;   // quad index
    const int n0q = QKVN*HID/4;
    const float* src = (i < n0q) ? wq : wo;
    int j = (i < n0q) ? i : i - n0q;
    f32x4 v = ((const f32x4*)src)[j];
    *(unsigned long long*)(wb + (size_t)i*4) = pk4bf(v[0], v[1], v[2], v[3]);
  } else if (bid < CVT_BLKS + RMS_BLKS) {
    int row = bid - CVT_BLKS;
    const f32x4* xr = (const f32x4*)(x + (size_t)row * HID);
    f32x4 v0 = {}, v1 = {};
    float ss = 0.f;
    if (tid < 192) {
      v0 = xr[2*tid]; v1 = xr[2*tid + 1];
      ss = v0[0]*v0[0] + v0[1]*v0[1] + v0[2]*v0[2] + v0[3]*v0[3]
         + v1[0]*v1[0] + v1[1]*v1[1] + v1[2]*v1[2] + v1[3]*v1[3];
    }
#pragma unroll
    for (int off = 1; off < 64; off <<= 1) ss += __shfl_xor(ss, off);
    __shared__ float red[4];
    if ((tid & 63) == 0) red[tid >> 6] = ss;
    __syncthreads();
    float rs = rsqrtf((red[0] + red[1] + red[2] + red[3]) * (1.f/HID) + 1e-6f);
    if (tid < 192) {
      const f32x4* gr = (const f32x4*)g;
      f32x4 g0 = gr[2*tid], g1 = gr[2*tid + 1];
      unsigned long long* out = (unsigned long long*)(xn + (size_t)row * HID);
      out[2*tid]     = pk4bf(v0[0]*rs*g0[0], v0[1]*rs*g0[1], v0[2]*rs*g0[2], v0[3]*rs*g0[3]);
      out[2*tid + 1] = pk4bf(v1[0]*rs*g1[0], v1[1]*rs*g1[1], v1[2]*rs*g1[2], v1[3]*rs*g1[3]);
    }
  } else {
    int i = (bid - CVT_BLKS - RMS_BLKS) * 256 + tid;   // [0, 65536)
    int s = i >> 5, p = i & 31;
    float t = (float)(spp[0] + s);
    // 10000^(-p/32) = exp2(-p*log2(1e4)/32)
    float inv = exp2f((float)p * -0.41524101186f);
    float sn, cs;
    sincosf(t * inv, &sn, &cs);
    tab[i] = make_float2(cs, sn);
  }
}

// ---------------- GEMM C[M][N] = A[M][K] @ W[N][K]^T, M fixed = 4096 ----------------
// R18: REVERT to the R15-verified config (BN=64, BK=64, vmcnt(6), 8-slot XOR
// swizzle, no min-waves bound -> 116 VGPR). R17's BK=32 experiment is CLOSED:
// it hit its occupancy goal (14->34%) but regressed 40->49us via 4.7M LDS
// bank-conflict cycles (4-way slot alias) + register starvation (VGPR 116->40
// killed ILP) + 2x barrier overhead per MFMA.
template <bool F32OUT>
__global__ __launch_bounds__(256) void k_gemm_bt(const u16* __restrict__ A,
                                                 const u16* __restrict__ W,
                                                 void* __restrict__ Cv,
                                                 const float* __restrict__ resid,
                                                 int N, int K) {
  __shared__ __align__(16) u16 As0[128*64], Bs0[64*64];
  __shared__ __align__(16) u16 As1[128*64], Bs1[64*64];
  int lin = blockIdx.x;
  int xcd = lin & 7, loc = lin >> 3;
  int mloc = loc & 3, nloc = loc >> 2;          // stripe height 4 (32 Mtiles / 8 XCDs)
  int m0 = (xcd*4 + mloc) * 128, n0 = nloc * 64;
  int tid = threadIdx.x;
  int w = tid >> 6, l = tid & 63;
  int wr = w >> 1, wc = w & 1;
  int c = l & 15, g = l >> 4;
  f32x4 acc[4][2] = {};
  int r8 = l >> 3;                  // row within the 8-row group = (row & 7)
  int sslot = (l & 7) ^ r8;         // swizzled 16B-slot index in the source row
  const u16* Ag = A + (size_t)(m0 + w*32 + r8)*K + sslot*8;   // 4 loads: rows w*32+i*8
  const u16* Wg = W + (size_t)(n0 + w*16 + r8)*K + sslot*8;   // 2 loads: rows w*16+i*8

#define STAGE(dA, dB, k0) do {                                                          \
  _Pragma("unroll")                                                                     \
  for (int i = 0; i < 4; i++)                                                           \
    __builtin_amdgcn_global_load_lds(                                                   \
        (const __attribute__((address_space(1))) void*)(Ag + (size_t)(i*8)*K + (k0)),   \
        (__attribute__((address_space(3))) void*)(dA + (w*32 + i*8)*64), 16, 0, 0);     \
  _Pragma("unroll")                                                                     \
  for (int i = 0; i < 2; i++)                                                           \
    __builtin_amdgcn_global_load_lds(                                                   \
        (const __attribute__((address_space(1))) void*)(Wg + (size_t)(i*8)*K + (k0)),   \
        (__attribute__((address_space(3))) void*)(dB + (w*16 + i*8)*64), 16, 0, 0);     \
  } while (0)

#define COMPUTE(sA, sB) do {                                                            \
  _Pragma("unroll")                                                                     \
  for (int ks = 0; ks < 2; ks++) {                                                      \
    s16x8 af[4], bq[2];                                                                 \
    int sl = ((ks*4 + g) ^ (c & 7)) * 8;                                                \
    _Pragma("unroll")                                                                   \
    for (int mt = 0; mt < 4; mt++)                                                      \
      af[mt] = *(const s16x8*)(sA + (wr*64 + mt*16 + c)*64 + sl);                       \
    _Pragma("unroll")                                                                   \
    for (int nt = 0; nt < 2; nt++)                                                      \
      bq[nt] = *(const s16x8*)(sB + (wc*32 + nt*16 + c)*64 + sl);                       \
    _Pragma("unroll")                                                                   \
    for (int mt = 0; mt < 4; mt++)                                                      \
      _Pragma("unroll")                                                                 \
      for (int nt = 0; nt < 2; nt++)                                                    \
        acc[mt][nt] = __builtin_amdgcn_mfma_f32_16x16x32_bf16(af[mt], bq[nt],           \
                                                              acc[mt][nt], 0, 0, 0);    \
  } } while (0)

  const int NT = K >> 6;            // 24 K-tiles of 64 (even, >= 4)
  STAGE(As0, Bs0, 0);
  STAGE(As1, Bs1, 64);
  WAITBAR(6);                       // tile0 landed; tile1 in flight
  for (int t = 0; t + 2 < NT; t += 2) {
    COMPUTE(As0, Bs0);              // tile t (landed)
    RAWBAR();                       // all waves done reading As0/Bs0
    STAGE(As0, Bs0, (t+2)*64);
    WAITBAR(6);                     // tile t+1 landed; t+2 in flight
    COMPUTE(As1, Bs1);              // tile t+1
    RAWBAR();                       // all waves done reading As1/Bs1
    if (t + 3 < NT) {
      STAGE(As1, Bs1, (t+3)*64);
      WAITBAR(6);                   // tile t+2 landed; t+3 in flight
    } else {
      WAITBAR(0);
    }
  }
  COMPUTE(As0, Bs0);                // tile NT-2 (landed via last WAITBAR)
  WAITBAR(0);                       // tile NT-1 landed
  COMPUTE(As1, Bs1);                // tile NT-1
#undef STAGE
#undef COMPUTE

#pragma unroll
  for (int mt = 0; mt < 4; mt++)
#pragma unroll
    for (int nt = 0; nt < 2; nt++)
#pragma unroll
      for (int r = 0; r < 4; r++) {
        int m = m0 + wr*64 + mt*16 + g*4 + r;
        int n = n0 + wc*32 + nt*16 + c;
        size_t off = (size_t)m*N + n;
        float vv = acc[mt][nt][r];
        if (F32OUT) {
          ((float*)Cv)[off] = vv + resid[off];
        } else {
          ((u16*)Cv)[off] = f2bf(vv);
        }
      }
}

// ---------------- fused RoPE(q,k) + V transpose (one launch) ----------------
// R16 (verified): table-based rotation; each thread does TWO rotation pairs.
__global__ __launch_bounds__(256) void k_rope_vt(const u16* __restrict__ qkv,
                                                 u16* __restrict__ q,
                                                 u16* __restrict__ k,
                                                 u16* __restrict__ vt,
                                                 const float2* __restrict__ tab) {
  __shared__ u16 tile[64][65];
  int bid = blockIdx.x;
  if (bid < ROPE2_BLOCKS) {
    int idx = bid * 256 + threadIdx.x;     // (tok*28 + h)*16 + j ; j covers p=2j,2j+1
    int j = idx & 15;
    int h = (idx >> 4) % 28;
    int tok = idx / 448;
    int s = tok & (S_ - 1);
    int b = tok >> 11;
    f32x4 cs = *(const f32x4*)(tab + (size_t)s*32 + 2*j);   // c0,s0,c1,s1 (16B aligned)
    int col = (h < NQ_) ? h*64 + 4*j : HID + (h - NQ_)*64 + 4*j;
    unsigned long long pr = *(const unsigned long long*)(qkv + (size_t)tok*QKVN + col);
    float x1a = bf2f((u16)pr),         x2a = bf2f((u16)(pr >> 16));
    float x1b = bf2f((u16)(pr >> 32)), x2b = bf2f((u16)(pr >> 48));
    float ya1 = x1a*cs[0] - x2a*cs[1];
    float ya2 = x2a*cs[0] + x1a*cs[1];
    float yb1 = x1b*cs[2] - x2b*cs[3];
    float yb2 = x2b*cs[2] + x1b*cs[3];
    unsigned long long outp = pk4bf(ya1, ya2, yb1, yb2);
    if (h < NQ_) {
      *(unsigned long long*)(q + (((size_t)(b*NQ_ + h))*S_ + s)*64 + 4*j) = outp;
    } else {
      *(unsigned long long*)(k + (((size_t)(b*NKV_ + (h - NQ_)))*S_ + s)*64 + 4*j) = outp;
    }
  } else {
    int blk = bid - ROPE2_BLOCKS;
    int st = blk & 31;
    int hk = (blk >> 5) & 3;
    int b = blk >> 7;
    int s0 = st * 64;
#pragma unroll
    for (int i = 0; i < 16; i++) {
      int ii = threadIdx.x + i*256;
      int r = ii >> 6, cc = ii & 63;
      tile[r][cc] = qkv[((size_t)(b*S_) + s0 + r)*QKVN + (NQ_+NKV_)*64 + hk*64 + cc];
    }
    __syncthreads();
#pragma unroll
    for (int i = 0; i < 16; i++) {
      int ii = threadIdx.x + i*256;
      int d = ii >> 6, s = ii & 63;
      vt[((size_t)(b*NKV_ + hk)*64 + d)*S_ + s0 + s] = tile[s][d];
    }
  }
}

// ---------------- Flash attention, one wave per (b,h,32-query tile) ----------------
// R4-exact structure (proven 43.4us) + R17 defer-max (T13, kept -- attn dropped
// below the top-5 cutoff with it): skip the alpha-exp and o/l rescale when no
// query's max grew by >8 (wave-uniform ballot). P bounded by e^8.
__global__ __launch_bounds__(64, 3) void k_attn(const u16* __restrict__ q,
                                                const u16* __restrict__ k,
                                                const u16* __restrict__ vt,
                                                u16* __restrict__ ao,
                                                const int* __restrict__ spp) {
  __shared__ __align__(16) u16 Pt[32*72];
  int lin = blockIdx.x;
  int xcd = lin & 7, loc = lin >> 3;
  int qb = loc & 63;
  int bh = xcd * 6 + (loc >> 6);   // [0,48)
  int h = bh % NQ_;
  int b = bh / NQ_;
  int q0 = qb * 32;
  int hk = h / (NQ_/NKV_);
  int l = threadIdx.x;
  int c = l & 15, g = l >> 4;
  int sp = spp[0];
  const u16* qptr = q + ((size_t)(b*NQ_ + h))*S_*64;
  const u16* kptr = k + ((size_t)(b*NKV_ + hk))*S_*64;
  const u16* vptr = vt + ((size_t)(b*NKV_ + hk))*64*S_;

  s16x8 qf[2][2];
#pragma unroll
  for (int qt = 0; qt < 2; qt++)
#pragma unroll
    for (int ks = 0; ks < 2; ks++)
      qf[qt][ks] = *(const s16x8*)(qptr + (size_t)(q0 + qt*16 + c)*64 + ks*32 + g*8);

  f32x4 o[4][2] = {};          // o[dt][qt]: O^T accum, row=d col=q
  float m_run[2], l_run[2];
#pragma unroll
  for (int i = 0; i < 2; i++) { m_run[i] = -1e30f; l_run[i] = 0.f; }

  int lo = sp + q0 - 256; if (lo < 0) lo = 0;
  int hi = sp + q0 + 31;  if (hi > S_ - 1) hi = S_ - 1;
  int kt0 = lo >> 6, kt1 = hi >> 6;

  s16x8 kf[4][2];
#pragma unroll
  for (int km = 0; km < 4; km++)
#pragma unroll
    for (int ks = 0; ks < 2; ks++)
      kf[km][ks] = *(const s16x8*)(kptr + (size_t)(kt0*64 + km*16 + c)*64 + ks*32 + g*8);

  for (int kt = kt0; kt <= kt1; kt++) {
    s16x8 vf[2][4];
#pragma unroll
    for (int ks = 0; ks < 2; ks++)
#pragma unroll
      for (int dt = 0; dt < 4; dt++)
        vf[ks][dt] = *(const s16x8*)(vptr + (size_t)(dt*16 + c)*S_ + kt*64 + ks*32 + g*8);

    bool full = (kt*64 + 63 <= sp + q0) && (kt*64 >= sp + q0 - 225);
#pragma unroll
    for (int qt = 0; qt < 2; qt++) {
      f32x4 sa[4];               // S^T slice for this qt: row=key col=query
      __builtin_amdgcn_s_setprio(1);
#pragma unroll
      for (int km = 0; km < 4; km++) {
        f32x4 z = {};
        z = __builtin_amdgcn_mfma_f32_16x16x32_bf16(kf[km][0], qf[qt][0], z, 0, 0, 0);
        sa[km] = __builtin_amdgcn_mfma_f32_16x16x32_bf16(kf[km][1], qf[qt][1], z, 0, 0, 0);
      }
      __builtin_amdgcn_s_setprio(0);
      if (qt == 1 && kt < kt1) {
#pragma unroll
        for (int km = 0; km < 4; km++)
#pragma unroll
          for (int ks = 0; ks < 2; ks++)
            kf[km][ks] = *(const s16x8*)(kptr + (size_t)((kt+1)*64 + km*16 + c)*64 + ks*32 + g*8);
      }
      float mx = -1e30f;
      if (full) {
#pragma unroll
        for (int km = 0; km < 4; km++)
#pragma unroll
          for (int r = 0; r < 4; r++) {
            float sv = sa[km][r] * 0.125f;
            sa[km][r] = sv;
            mx = fmaxf(mx, sv);
          }
      } else {
        int pos = sp + q0 + qt*16 + c;
#pragma unroll
        for (int km = 0; km < 4; km++)
#pragma unroll
          for (int r = 0; r < 4; r++) {
            int key = kt*64 + km*16 + g*4 + r;
            float sv = sa[km][r] * 0.125f;
            sv = ((unsigned)(pos - key) <= 256u) ? sv : -1e30f;
            sa[km][r] = sv;
            mx = fmaxf(mx, sv);
          }
      }
      mx = fmaxf(mx, __shfl_xor(mx, 16));
      mx = fmaxf(mx, __shfl_xor(mx, 32));
      // T13 defer-max: only rescale when some query's max grew by >8.
      if (__ballot(mx > m_run[qt] + 8.f) != 0) {
        float mnew = fmaxf(m_run[qt], mx);
        float alpha = __expf(m_run[qt] - mnew);
        m_run[qt] = mnew;
        l_run[qt] *= alpha;
#pragma unroll
        for (int dt = 0; dt < 4; dt++) {
          o[dt][qt][0] *= alpha; o[dt][qt][1] *= alpha;
          o[dt][qt][2] *= alpha; o[dt][qt][3] *= alpha;
        }
      }
      float mref = m_run[qt];
      float rsum = 0.f;
#pragma unroll
      for (int km = 0; km < 4; km++) {
        float p0 = __expf(sa[km][0] - mref);   // masked -1e30 underflows to 0
        float p1 = __expf(sa[km][1] - mref);
        float p2 = __expf(sa[km][2] - mref);
        float p3 = __expf(sa[km][3] - mref);
        rsum += p0 + p1 + p2 + p3;
        *(unsigned long long*)(Pt + (qt*16 + c)*72 + km*16 + g*4) = pk4bf(p0, p1, p2, p3);
      }
      rsum += __shfl_xor(rsum, 16);
      rsum += __shfl_xor(rsum, 32);
      l_run[qt] += rsum;
    }
    LDS_FENCE();   // Pt writes ordered before reads (in-order DS pipe, same wave)
    // PV: O^T += V^T @ P^T
    __builtin_amdgcn_s_setprio(1);
#pragma unroll
    for (int ks = 0; ks < 2; ks++)
#pragma unroll
      for (int qt = 0; qt < 2; qt++) {
        s16x8 pf = *(const s16x8*)(Pt + (qt*16 + c)*72 + ks*32 + g*8);
#pragma unroll
        for (int dt = 0; dt < 4; dt++)
          o[dt][qt] = __builtin_amdgcn_mfma_f32_16x16x32_bf16(vf[ks][dt], pf, o[dt][qt], 0, 0, 0);
      }
    __builtin_amdgcn_s_setprio(0);
    LDS_FENCE();   // Pt reads ordered before next iteration's writes
  }
#pragma unroll
  for (int qt = 0; qt < 2; qt++) {
    float inv = 1.f / l_run[qt];
    int qi = q0 + qt*16 + c;
    u16* row = ao + ((size_t)(b*S_) + qi)*HID + h*64;
#pragma unroll
    for (int dt = 0; dt < 4; dt++)
      *(unsigned long long*)(row + dt*16 + g*4) =
          pk4bf(o[dt][qt][0]*inv, o[dt][qt][1]*inv, o[dt][qt][2]*inv, o[dt][qt][3]*inv);
  }
}

extern "C" void kernel_launch(void* const* d_in, const int* in_sizes, int n_in,
                              void* d_out, int out_size, void* d_ws, size_t ws_size,
                              hipStream_t stream) {
  const float* x_f32    = (const float*)d_in[0];
  const float* g_f32    = (const float*)d_in[1];
  const float* wqkv_f32 = (const float*)d_in[2];
  const float* wout_f32 = (const float*)d_in[3];
  const int*   spp      = (const int*)d_in[4];
  char* ws = (char*)d_ws;
  // workspace layout (bytes), ~57.1 MB total
  u16* wqkvb = (u16*)(ws);                    //  6,291,456
  u16* woutb = (u16*)(ws + 6291456);          //  4,718,592 (contiguous with wqkvb)
  u16* xn    = (u16*)(ws + 11010048);         // 12,582,912
  u16* qkv   = (u16*)(ws + 23592960);         // 16,777,216
  u16* qbuf  = (u16*)(ws + 40370176);         // 12,582,912
  u16* kbuf  = (u16*)(ws + 52953088);         //  2,097,152
  u16* vtb   = (u16*)(ws + 55050240);         //  2,097,152  (end 57,147,392)
  u16* attn  = xn;                            // aliases xn (dead after GEMM1)
  // RoPE table lives in d_out's buffer (512KB of 25MB; dead until GEMM2 writes it)
  float2* tab = (float2*)d_out;

  k_setup<<<SETUP_BLKS, 256, 0, stream>>>(x_f32, g_f32, wqkv_f32, wout_f32,
                                          wqkvb, xn, tab, spp);
  k_gemm_bt<false><<<32*(QKVN/64), 256, 0, stream>>>(xn, wqkvb, qkv, nullptr, QKVN, HID);
  k_rope_vt<<<ROPE2_BLOCKS + VT_BLOCKS, 256, 0, stream>>>(qkv, qbuf, kbuf, vtb,
                                                          (const float2*)tab);
  k_attn<<<B_*NQ_*(S_/32), 64, 0, stream>>>(qbuf, kbuf, vtb, attn, spp);
  k_gemm_bt<true><<<32*(HID/64), 256, 0, stream>>>(attn, woutb, d_out, x_f32, HID, HID);
}

// Round 16
// 200.546 us; speedup vs baseline: 1.0782x; 1.0116x over previous
//
#include <hip/hip_runtime.h>
#include <hip/hip_bf16.h>

typedef float f32x4 __attribute__((ext_vector_type(4)));
typedef short s16x8 __attribute__((ext_vector_type(8)));
typedef unsigned short u16;

#define B_ 2
#define S_ 2048
#define HID 1536
#define NQ_ 24
#define NKV_ 4
#define HD 64
#define NTOK (B_*S_)
#define QKVN ((NQ_+2*NKV_)*HD)   // 2048

// fused setup kernel job split
#define CVT_BLKS  ((QKVN*HID + HID*HID)/4/256)   // 5376
#define RMS_BLKS  NTOK                            // 4096
#define TAB_BLKS  (S_*32/256)                     // 256
#define SETUP_BLKS (CVT_BLKS + RMS_BLKS + TAB_BLKS)

// Compiler-only memory fence (single-wave block: LDS pipe is in-order, no s_barrier
// needed -> avoids the vmcnt(0) drain). Proven R6->R7 on k_attn.
#define LDS_FENCE() asm volatile("" ::: "memory")

// Counted-vmcnt barrier pair (T4): wait for all but the newest N loads, then raw
// s_barrier -- deliberately does NOT drain the in-flight prefetch.
#define WAITBAR(n) asm volatile("s_waitcnt vmcnt(" #n ")\n\ts_barrier" ::: "memory")
#define RAWBAR()   asm volatile("s_barrier" ::: "memory")

__device__ __forceinline__ float bf2f(u16 u) {
  unsigned int x = ((unsigned int)u) << 16;
  float f; __builtin_memcpy(&f, &x, 4); return f;
}
__device__ __forceinline__ u16 f2bf(float f) {
  unsigned int u; __builtin_memcpy(&u, &f, 4);
  u += 0x7fffu + ((u >> 16) & 1u);
  return (u16)(u >> 16);
}
// 4x f32 -> packed bf16x4 via v_cvt_pk_bf16_f32
__device__ __forceinline__ unsigned long long pk4bf(float a, float b, float c, float d) {
  __hip_bfloat162 x = __float22bfloat162_rn(make_float2(a, b));
  __hip_bfloat162 y = __float22bfloat162_rn(make_float2(c, d));
  unsigned int xi, yi;
  __builtin_memcpy(&xi, &x, 4);
  __builtin_memcpy(&yi, &y, 4);
  return (unsigned long long)xi | ((unsigned long long)yi << 32);
}

// ---------------- fused setup: weight cvt + RMSNorm + RoPE cos/sin table ----------------
// R16 (verified): one launch, block-range-split jobs. Table lives in d_out's buffer
// (dead until GEMM2 writes it; only read by GEMM1's epilogue, which runs earlier).
__global__ __launch_bounds__(256) void k_setup(const float* __restrict__ x,
                                               const float* __restrict__ g,
                                               const float* __restrict__ wq,
                                               const float* __restrict__ wo,
                                               u16* __restrict__ wb,
                                               u16* __restrict__ xn,
                                               float2* __restrict__ tab,
                                               const int* __restrict__ spp) {
  int bid = blockIdx.x, tid = threadIdx.x;
  if (bid < CVT_BLKS) {
    int i = bid * 256 + tid;   // quad index
    const int n0q = QKVN*HID/4;
    const float* src = (i < n0q) ? wq : wo;
    int j = (i < n0q) ? i : i - n0q;
    f32x4 v = ((const f32x4*)src)[j];
    *(unsigned long long*)(wb + (size_t)i*4) = pk4bf(v[0], v[1], v[2], v[3]);
  } else if (bid < CVT_BLKS + RMS_BLKS) {
    int row = bid - CVT_BLKS;
    const f32x4* xr = (const f32x4*)(x + (size_t)row * HID);
    f32x4 v0 = {}, v1 = {};
    float ss = 0.f;
    if (tid < 192) {
      v0 = xr[2*tid]; v1 = xr[2*tid + 1];
      ss = v0[0]*v0[0] + v0[1]*v0[1] + v0[2]*v0[2] + v0[3]*v0[3]
         + v1[0]*v1[0] + v1[1]*v1[1] + v1[2]*v1[2] + v1[3]*v1[3];
    }
#pragma unroll
    for (int off = 1; off < 64; off <<= 1) ss += __shfl_xor(ss, off);
    __shared__ float red[4];
    if ((tid & 63) == 0) red[tid >> 6] = ss;
    __syncthreads();
    float rs = rsqrtf((red[0] + red[1] + red[2] + red[3]) * (1.f/HID) + 1e-6f);
    if (tid < 192) {
      const f32x4* gr = (const f32x4*)g;
      f32x4 g0 = gr[2*tid], g1 = gr[2*tid + 1];
      unsigned long long* out = (unsigned long long*)(xn + (size_t)row * HID);
      out[2*tid]     = pk4bf(v0[0]*rs*g0[0], v0[1]*rs*g0[1], v0[2]*rs*g0[2], v0[3]*rs*g0[3]);
      out[2*tid + 1] = pk4bf(v1[0]*rs*g1[0], v1[1]*rs*g1[1], v1[2]*rs*g1[2], v1[3]*rs*g1[3]);
    }
  } else {
    int i = (bid - CVT_BLKS - RMS_BLKS) * 256 + tid;   // [0, 65536)
    int s = i >> 5, p = i & 31;
    float t = (float)(spp[0] + s);
    // 10000^(-p/32) = exp2(-p*log2(1e4)/32)
    float inv = exp2f((float)p * -0.41524101186f);
    float sn, cs;
    sincosf(t * inv, &sn, &cs);
    tab[i] = make_float2(cs, sn);
  }
}

// ---------------- GEMM C[M][N] = A[M][K] @ W[N][K]^T, M fixed = 4096 ----------------
// R15-verified main loop (BN=64, BK=64, vmcnt(6), 8-slot XOR swizzle, XCD M-stripe).
// R19: MODE 0 fuses RoPE + Q/K scatter + V transpose into the epilogue:
//  - thread's C value at (token m, col n): s=m&2047, b=m>>11, h=n>>6, d=n&63
//  - RoPE pair (n, n^1) lives in the adjacent lane -> one __shfl_xor(acc,1)
//  - cos/sin from the R16 table (L2-resident, 8B loads)
//  - V (d-major) gets 4 consecutive s at fixed d -> contiguous 8B store; the
//    LDS-transpose kernel (k_rope_vt) is deleted entirely: saves a launch +
//    the 16.8MB qkv read (rotation now on f32 acc = slightly more accurate).
// MODE 1: f32 out + residual (GEMM2), unchanged.
template <int MODE>
__global__ __launch_bounds__(256) void k_gemm_bt(const u16* __restrict__ A,
                                                 const u16* __restrict__ W,
                                                 void* __restrict__ Cv,
                                                 const float* __restrict__ resid,
                                                 const float2* __restrict__ tab,
                                                 u16* __restrict__ qp,
                                                 u16* __restrict__ kp,
                                                 u16* __restrict__ vp,
                                                 int N, int K) {
  __shared__ __align__(16) u16 As0[128*64], Bs0[64*64];
  __shared__ __align__(16) u16 As1[128*64], Bs1[64*64];
  int lin = blockIdx.x;
  int xcd = lin & 7, loc = lin >> 3;
  int mloc = loc & 3, nloc = loc >> 2;          // stripe height 4 (32 Mtiles / 8 XCDs)
  int m0 = (xcd*4 + mloc) * 128, n0 = nloc * 64;
  int tid = threadIdx.x;
  int w = tid >> 6, l = tid & 63;
  int wr = w >> 1, wc = w & 1;
  int c = l & 15, g = l >> 4;
  f32x4 acc[4][2] = {};
  int r8 = l >> 3;                  // row within the 8-row group = (row & 7)
  int sslot = (l & 7) ^ r8;         // swizzled 16B-slot index in the source row
  const u16* Ag = A + (size_t)(m0 + w*32 + r8)*K + sslot*8;   // 4 loads: rows w*32+i*8
  const u16* Wg = W + (size_t)(n0 + w*16 + r8)*K + sslot*8;   // 2 loads: rows w*16+i*8

#define STAGE(dA, dB, k0) do {                                                          \
  _Pragma("unroll")                                                                     \
  for (int i = 0; i < 4; i++)                                                           \
    __builtin_amdgcn_global_load_lds(                                                   \
        (const __attribute__((address_space(1))) void*)(Ag + (size_t)(i*8)*K + (k0)),   \
        (__attribute__((address_space(3))) void*)(dA + (w*32 + i*8)*64), 16, 0, 0);     \
  _Pragma("unroll")                                                                     \
  for (int i = 0; i < 2; i++)                                                           \
    __builtin_amdgcn_global_load_lds(                                                   \
        (const __attribute__((address_space(1))) void*)(Wg + (size_t)(i*8)*K + (k0)),   \
        (__attribute__((address_space(3))) void*)(dB + (w*16 + i*8)*64), 16, 0, 0);     \
  } while (0)

#define COMPUTE(sA, sB) do {                                                            \
  _Pragma("unroll")                                                                     \
  for (int ks = 0; ks < 2; ks++) {                                                      \
    s16x8 af[4], bq[2];                                                                 \
    int sl = ((ks*4 + g) ^ (c & 7)) * 8;                                                \
    _Pragma("unroll")                                                                   \
    for (int mt = 0; mt < 4; mt++)                                                      \
      af[mt] = *(const s16x8*)(sA + (wr*64 + mt*16 + c)*64 + sl);                       \
    _Pragma("unroll")                                                                   \
    for (int nt = 0; nt < 2; nt++)                                                      \
      bq[nt] = *(const s16x8*)(sB + (wc*32 + nt*16 + c)*64 + sl);                       \
    _Pragma("unroll")                                                                   \
    for (int mt = 0; mt < 4; mt++)                                                      \
      _Pragma("unroll")                                                                 \
      for (int nt = 0; nt < 2; nt++)                                                    \
        acc[mt][nt] = __builtin_amdgcn_mfma_f32_16x16x32_bf16(af[mt], bq[nt],           \
                                                              acc[mt][nt], 0, 0, 0);    \
  } } while (0)

  const int NT = K >> 6;            // 24 K-tiles of 64 (even, >= 4)
  STAGE(As0, Bs0, 0);
  STAGE(As1, Bs1, 64);
  WAITBAR(6);                       // tile0 landed; tile1 in flight
  for (int t = 0; t + 2 < NT; t += 2) {
    COMPUTE(As0, Bs0);              // tile t (landed)
    RAWBAR();                       // all waves done reading As0/Bs0
    STAGE(As0, Bs0, (t+2)*64);
    WAITBAR(6);                     // tile t+1 landed; t+2 in flight
    COMPUTE(As1, Bs1);              // tile t+1
    RAWBAR();                       // all waves done reading As1/Bs1
    if (t + 3 < NT) {
      STAGE(As1, Bs1, (t+3)*64);
      WAITBAR(6);                   // tile t+2 landed; t+3 in flight
    } else {
      WAITBAR(0);
    }
  }
  COMPUTE(As0, Bs0);                // tile NT-2 (landed via last WAITBAR)
  WAITBAR(0);                       // tile NT-1 landed
  COMPUTE(As1, Bs1);                // tile NT-1
#undef STAGE
#undef COMPUTE

#pragma unroll
  for (int mt = 0; mt < 4; mt++)
#pragma unroll
    for (int nt = 0; nt < 2; nt++) {
      if (MODE == 1) {
#pragma unroll
        for (int r = 0; r < 4; r++) {
          int m = m0 + wr*64 + mt*16 + g*4 + r;
          int n = n0 + wc*32 + nt*16 + c;
          size_t off = (size_t)m*N + n;
          ((float*)Cv)[off] = acc[mt][nt][r] + resid[off];
        }
      } else {
        int n = n0 + wc*32 + nt*16 + c;
        int d = n & 63;
        // partner value for the RoPE pair lives in lane l^1 (adjacent column)
        f32x4 px;
#pragma unroll
        for (int r = 0; r < 4; r++) px[r] = __shfl_xor(acc[mt][nt][r], 1);
        if (n < NQ_*HD) {                          // ---- Q: rope + scatter
          int h = n >> 6;
#pragma unroll
          for (int r = 0; r < 4; r++) {
            int m = m0 + wr*64 + mt*16 + g*4 + r;
            int s = m & (S_-1), bb = m >> 11;
            float2 t2 = tab[s*32 + (d >> 1)];
            float y = (n & 1) ? acc[mt][nt][r]*t2.x + px[r]*t2.y
                              : acc[mt][nt][r]*t2.x - px[r]*t2.y;
            qp[(((size_t)(bb*NQ_ + h))*S_ + s)*64 + d] = f2bf(y);
          }
        } else if (n < (NQ_+NKV_)*HD) {            // ---- K: rope + scatter
          int hk = (n >> 6) - NQ_;
#pragma unroll
          for (int r = 0; r < 4; r++) {
            int m = m0 + wr*64 + mt*16 + g*4 + r;
            int s = m & (S_-1), bb = m >> 11;
            float2 t2 = tab[s*32 + (d >> 1)];
            float y = (n & 1) ? acc[mt][nt][r]*t2.x + px[r]*t2.y
                              : acc[mt][nt][r]*t2.x - px[r]*t2.y;
            kp[(((size_t)(bb*NKV_ + hk))*S_ + s)*64 + d] = f2bf(y);
          }
        } else {                                   // ---- V: transpose store (free)
          int hk = (n >> 6) - (NQ_+NKV_);
          int m = m0 + wr*64 + mt*16 + g*4;        // 4 consecutive tokens
          int s = m & (S_-1), bb = m >> 11;
          *(unsigned long long*)(vp + (((size_t)(bb*NKV_ + hk))*64 + d)*S_ + s) =
              pk4bf(acc[mt][nt][0], acc[mt][nt][1], acc[mt][nt][2], acc[mt][nt][3]);
        }
      }
    }
}

// ---------------- Flash attention, one wave per (b,h,32-query tile) ----------------
// R4-exact structure (proven 43.4us) + R17 defer-max (T13, verified ~ -1.4us):
// skip the alpha-exp and o/l rescale when no query's max grew by >8.
__global__ __launch_bounds__(64, 3) void k_attn(const u16* __restrict__ q,
                                                const u16* __restrict__ k,
                                                const u16* __restrict__ vt,
                                                u16* __restrict__ ao,
                                                const int* __restrict__ spp) {
  __shared__ __align__(16) u16 Pt[32*72];
  int lin = blockIdx.x;
  int xcd = lin & 7, loc = lin >> 3;
  int qb = loc & 63;
  int bh = xcd * 6 + (loc >> 6);   // [0,48)
  int h = bh % NQ_;
  int b = bh / NQ_;
  int q0 = qb * 32;
  int hk = h / (NQ_/NKV_);
  int l = threadIdx.x;
  int c = l & 15, g = l >> 4;
  int sp = spp[0];
  const u16* qptr = q + ((size_t)(b*NQ_ + h))*S_*64;
  const u16* kptr = k + ((size_t)(b*NKV_ + hk))*S_*64;
  const u16* vptr = vt + ((size_t)(b*NKV_ + hk))*64*S_;

  s16x8 qf[2][2];
#pragma unroll
  for (int qt = 0; qt < 2; qt++)
#pragma unroll
    for (int ks = 0; ks < 2; ks++)
      qf[qt][ks] = *(const s16x8*)(qptr + (size_t)(q0 + qt*16 + c)*64 + ks*32 + g*8);

  f32x4 o[4][2] = {};          // o[dt][qt]: O^T accum, row=d col=q
  float m_run[2], l_run[2];
#pragma unroll
  for (int i = 0; i < 2; i++) { m_run[i] = -1e30f; l_run[i] = 0.f; }

  int lo = sp + q0 - 256; if (lo < 0) lo = 0;
  int hi = sp + q0 + 31;  if (hi > S_ - 1) hi = S_ - 1;
  int kt0 = lo >> 6, kt1 = hi >> 6;

  s16x8 kf[4][2];
#pragma unroll
  for (int km = 0; km < 4; km++)
#pragma unroll
    for (int ks = 0; ks < 2; ks++)
      kf[km][ks] = *(const s16x8*)(kptr + (size_t)(kt0*64 + km*16 + c)*64 + ks*32 + g*8);

  for (int kt = kt0; kt <= kt1; kt++) {
    s16x8 vf[2][4];
#pragma unroll
    for (int ks = 0; ks < 2; ks++)
#pragma unroll
      for (int dt = 0; dt < 4; dt++)
        vf[ks][dt] = *(const s16x8*)(vptr + (size_t)(dt*16 + c)*S_ + kt*64 + ks*32 + g*8);

    bool full = (kt*64 + 63 <= sp + q0) && (kt*64 >= sp + q0 - 225);
#pragma unroll
    for (int qt = 0; qt < 2; qt++) {
      f32x4 sa[4];               // S^T slice for this qt: row=key col=query
      __builtin_amdgcn_s_setprio(1);
#pragma unroll
      for (int km = 0; km < 4; km++) {
        f32x4 z = {};
        z = __builtin_amdgcn_mfma_f32_16x16x32_bf16(kf[km][0], qf[qt][0], z, 0, 0, 0);
        sa[km] = __builtin_amdgcn_mfma_f32_16x16x32_bf16(kf[km][1], qf[qt][1], z, 0, 0, 0);
      }
      __builtin_amdgcn_s_setprio(0);
      if (qt == 1 && kt < kt1) {
#pragma unroll
        for (int km = 0; km < 4; km++)
#pragma unroll
          for (int ks = 0; ks < 2; ks++)
            kf[km][ks] = *(const s16x8*)(kptr + (size_t)((kt+1)*64 + km*16 + c)*64 + ks*32 + g*8);
      }
      float mx = -1e30f;
      if (full) {
#pragma unroll
        for (int km = 0; km < 4; km++)
#pragma unroll
          for (int r = 0; r < 4; r++) {
            float sv = sa[km][r] * 0.125f;
            sa[km][r] = sv;
            mx = fmaxf(mx, sv);
          }
      } else {
        int pos = sp + q0 + qt*16 + c;
#pragma unroll
        for (int km = 0; km < 4; km++)
#pragma unroll
          for (int r = 0; r < 4; r++) {
            int key = kt*64 + km*16 + g*4 + r;
            float sv = sa[km][r] * 0.125f;
            sv = ((unsigned)(pos - key) <= 256u) ? sv : -1e30f;
            sa[km][r] = sv;
            mx = fmaxf(mx, sv);
          }
      }
      mx = fmaxf(mx, __shfl_xor(mx, 16));
      mx = fmaxf(mx, __shfl_xor(mx, 32));
      // T13 defer-max: only rescale when some query's max grew by >8.
      if (__ballot(mx > m_run[qt] + 8.f) != 0) {
        float mnew = fmaxf(m_run[qt], mx);
        float alpha = __expf(m_run[qt] - mnew);
        m_run[qt] = mnew;
        l_run[qt] *= alpha;
#pragma unroll
        for (int dt = 0; dt < 4; dt++) {
          o[dt][qt][0] *= alpha; o[dt][qt][1] *= alpha;
          o[dt][qt][2] *= alpha; o[dt][qt][3] *= alpha;
        }
      }
      float mref = m_run[qt];
      float rsum = 0.f;
#pragma unroll
      for (int km = 0; km < 4; km++) {
        float p0 = __expf(sa[km][0] - mref);   // masked -1e30 underflows to 0
        float p1 = __expf(sa[km][1] - mref);
        float p2 = __expf(sa[km][2] - mref);
        float p3 = __expf(sa[km][3] - mref);
        rsum += p0 + p1 + p2 + p3;
        *(unsigned long long*)(Pt + (qt*16 + c)*72 + km*16 + g*4) = pk4bf(p0, p1, p2, p3);
      }
      rsum += __shfl_xor(rsum, 16);
      rsum += __shfl_xor(rsum, 32);
      l_run[qt] += rsum;
    }
    LDS_FENCE();   // Pt writes ordered before reads (in-order DS pipe, same wave)
    // PV: O^T += V^T @ P^T
    __builtin_amdgcn_s_setprio(1);
#pragma unroll
    for (int ks = 0; ks < 2; ks++)
#pragma unroll
      for (int qt = 0; qt < 2; qt++) {
        s16x8 pf = *(const s16x8*)(Pt + (qt*16 + c)*72 + ks*32 + g*8);
#pragma unroll
        for (int dt = 0; dt < 4; dt++)
          o[dt][qt] = __builtin_amdgcn_mfma_f32_16x16x32_bf16(vf[ks][dt], pf, o[dt][qt], 0, 0, 0);
      }
    __builtin_amdgcn_s_setprio(0);
    LDS_FENCE();   // Pt reads ordered before next iteration's writes
  }
#pragma unroll
  for (int qt = 0; qt < 2; qt++) {
    float inv = 1.f / l_run[qt];
    int qi = q0 + qt*16 + c;
    u16* row = ao + ((size_t)(b*S_) + qi)*HID + h*64;
#pragma unroll
    for (int dt = 0; dt < 4; dt++)
      *(unsigned long long*)(row + dt*16 + g*4) =
          pk4bf(o[dt][qt][0]*inv, o[dt][qt][1]*inv, o[dt][qt][2]*inv, o[dt][qt][3]*inv);
  }
}

extern "C" void kernel_launch(void* const* d_in, const int* in_sizes, int n_in,
                              void* d_out, int out_size, void* d_ws, size_t ws_size,
                              hipStream_t stream) {
  const float* x_f32    = (const float*)d_in[0];
  const float* g_f32    = (const float*)d_in[1];
  const float* wqkv_f32 = (const float*)d_in[2];
  const float* wout_f32 = (const float*)d_in[3];
  const int*   spp      = (const int*)d_in[4];
  char* ws = (char*)d_ws;
  // workspace layout (bytes)
  u16* wqkvb = (u16*)(ws);                    //  6,291,456
  u16* woutb = (u16*)(ws + 6291456);          //  4,718,592 (contiguous with wqkvb)
  u16* xn    = (u16*)(ws + 11010048);         // 12,582,912
  u16* qbuf  = (u16*)(ws + 40370176);         // 12,582,912
  u16* kbuf  = (u16*)(ws + 52953088);         //  2,097,152
  u16* vtb   = (u16*)(ws + 55050240);         //  2,097,152  (end 57,147,392)
  u16* attn  = xn;                            // aliases xn (dead after GEMM1)
  // RoPE table lives in d_out's buffer (512KB of 25MB); read only by GEMM1's
  // epilogue, which completes before GEMM2 overwrites d_out (stream-ordered).
  float2* tab = (float2*)d_out;

  k_setup<<<SETUP_BLKS, 256, 0, stream>>>(x_f32, g_f32, wqkv_f32, wout_f32,
                                          wqkvb, xn, tab, spp);
  k_gemm_bt<0><<<32*(QKVN/64), 256, 0, stream>>>(xn, wqkvb, nullptr, nullptr,
                                                 (const float2*)tab, qbuf, kbuf, vtb,
                                                 QKVN, HID);
  k_attn<<<B_*NQ_*(S_/32), 64, 0, stream>>>(qbuf, kbuf, vtb, attn, spp);
  k_gemm_bt<1><<<32*(HID/64), 256, 0, stream>>>(attn, woutb, d_out, x_f32,
                                                nullptr, nullptr, nullptr, nullptr,
                                                HID, HID);
}

// Round 17
// 198.103 us; speedup vs baseline: 1.0915x; 1.0123x over previous
//
#include <hip/hip_runtime.h>
#include <hip/hip_bf16.h>

typedef float f32x4 __attribute__((ext_vector_type(4)));
typedef short s16x8 __attribute__((ext_vector_type(8)));
typedef unsigned short u16;

#define B_ 2
#define S_ 2048
#define HID 1536
#define NQ_ 24
#define NKV_ 4
#define HD 64
#define NTOK (B_*S_)
#define QKVN ((NQ_+2*NKV_)*HD)   // 2048

// fused setup kernel job split
#define CVT_BLKS  ((QKVN*HID + HID*HID)/4/256)   // 5376
#define RMS_BLKS  NTOK                            // 4096
#define TAB_BLKS  (S_*32/256)                     // 256
#define SETUP_BLKS (CVT_BLKS + RMS_BLKS + TAB_BLKS)

// Compiler-only memory fence (single-wave block: LDS pipe is in-order, no s_barrier
// needed -> avoids the vmcnt(0) drain). Proven R6->R7 on k_attn.
#define LDS_FENCE() asm volatile("" ::: "memory")

// Counted-vmcnt barrier pair (T4): wait for all but the newest N loads, then raw
// s_barrier -- deliberately does NOT drain the in-flight prefetch.
#define WAITBAR(n) asm volatile("s_waitcnt vmcnt(" #n ")\n\ts_barrier" ::: "memory")
#define RAWBAR()   asm volatile("s_barrier" ::: "memory")

__device__ __forceinline__ float bf2f(u16 u) {
  unsigned int x = ((unsigned int)u) << 16;
  float f; __builtin_memcpy(&f, &x, 4); return f;
}
__device__ __forceinline__ u16 f2bf(float f) {
  unsigned int u; __builtin_memcpy(&u, &f, 4);
  u += 0x7fffu + ((u >> 16) & 1u);
  return (u16)(u >> 16);
}
// 4x f32 -> packed bf16x4 via v_cvt_pk_bf16_f32
__device__ __forceinline__ unsigned long long pk4bf(float a, float b, float c, float d) {
  __hip_bfloat162 x = __float22bfloat162_rn(make_float2(a, b));
  __hip_bfloat162 y = __float22bfloat162_rn(make_float2(c, d));
  unsigned int xi, yi;
  __builtin_memcpy(&xi, &x, 4);
  __builtin_memcpy(&yi, &y, 4);
  return (unsigned long long)xi | ((unsigned long long)yi << 32);
}

// ---------------- fused setup: weight cvt + RMSNorm + RoPE cos/sin table ----------------
// R16 (verified): one launch, block-range-split jobs. Table lives in d_out's buffer
// (dead until GEMM2 writes it; only read by GEMM1's epilogue, which runs earlier).
__global__ __launch_bounds__(256) void k_setup(const float* __restrict__ x,
                                               const float* __restrict__ g,
                                               const float* __restrict__ wq,
                                               const float* __restrict__ wo,
                                               u16* __restrict__ wb,
                                               u16* __restrict__ xn,
                                               float2* __restrict__ tab,
                                               const int* __restrict__ spp) {
  int bid = blockIdx.x, tid = threadIdx.x;
  if (bid < CVT_BLKS) {
    int i = bid * 256 + tid;   // quad index
    const int n0q = QKVN*HID/4;
    const float* src = (i < n0q) ? wq : wo;
    int j = (i < n0q) ? i : i - n0q;
    f32x4 v = ((const f32x4*)src)[j];
    *(unsigned long long*)(wb + (size_t)i*4) = pk4bf(v[0], v[1], v[2], v[3]);
  } else if (bid < CVT_BLKS + RMS_BLKS) {
    int row = bid - CVT_BLKS;
    const f32x4* xr = (const f32x4*)(x + (size_t)row * HID);
    f32x4 v0 = {}, v1 = {};
    float ss = 0.f;
    if (tid < 192) {
      v0 = xr[2*tid]; v1 = xr[2*tid + 1];
      ss = v0[0]*v0[0] + v0[1]*v0[1] + v0[2]*v0[2] + v0[3]*v0[3]
         + v1[0]*v1[0] + v1[1]*v1[1] + v1[2]*v1[2] + v1[3]*v1[3];
    }
#pragma unroll
    for (int off = 1; off < 64; off <<= 1) ss += __shfl_xor(ss, off);
    __shared__ float red[4];
    if ((tid & 63) == 0) red[tid >> 6] = ss;
    __syncthreads();
    float rs = rsqrtf((red[0] + red[1] + red[2] + red[3]) * (1.f/HID) + 1e-6f);
    if (tid < 192) {
      const f32x4* gr = (const f32x4*)g;
      f32x4 g0 = gr[2*tid], g1 = gr[2*tid + 1];
      unsigned long long* out = (unsigned long long*)(xn + (size_t)row * HID);
      out[2*tid]     = pk4bf(v0[0]*rs*g0[0], v0[1]*rs*g0[1], v0[2]*rs*g0[2], v0[3]*rs*g0[3]);
      out[2*tid + 1] = pk4bf(v1[0]*rs*g1[0], v1[1]*rs*g1[1], v1[2]*rs*g1[2], v1[3]*rs*g1[3]);
    }
  } else {
    int i = (bid - CVT_BLKS - RMS_BLKS) * 256 + tid;   // [0, 65536)
    int s = i >> 5, p = i & 31;
    float t = (float)(spp[0] + s);
    // 10000^(-p/32) = exp2(-p*log2(1e4)/32)
    float inv = exp2f((float)p * -0.41524101186f);
    float sn, cs;
    sincosf(t * inv, &sn, &cs);
    tab[i] = make_float2(cs, sn);
  }
}

// ---------------- GEMM C[M][N] = A[M][K] @ W[N][K]^T, M fixed = 4096 ----------------
// R20: depth-2 triple-buffered pipeline (true T3/T4). The depth-1 schedule gave
// tile t+1's loads only ~one COMPUTE (~300cy) of cover vs ~1000+cy latency; R15
// compensated with a 3rd resident block. m218's lesson: counted vmcnt with loads
// spanning MULTIPLE phases is the real lever. Here: prologue stages tiles 0,1,2;
// each step computes t, re-stages buf(t%3) with t+3, waits vmcnt(12) (= 2 stages
// in flight, oldest landed) -> every tile gets ~2 COMPUTE phases of cover.
// LDS 72KB -> 2 blocks/CU (trades a block for depth; that's the experiment).
// NT=24 divisible by 3 -> exact schedule. MODE 0: fused RoPE/Q/K/V epilogue (R19).
template <int MODE>
__global__ __launch_bounds__(256) void k_gemm_bt(const u16* __restrict__ A,
                                                 const u16* __restrict__ W,
                                                 void* __restrict__ Cv,
                                                 const float* __restrict__ resid,
                                                 const float2* __restrict__ tab,
                                                 u16* __restrict__ qp,
                                                 u16* __restrict__ kp,
                                                 u16* __restrict__ vp,
                                                 int N, int K) {
  __shared__ __align__(16) u16 As0[128*64], Bs0[64*64];
  __shared__ __align__(16) u16 As1[128*64], Bs1[64*64];
  __shared__ __align__(16) u16 As2[128*64], Bs2[64*64];
  int lin = blockIdx.x;
  int xcd = lin & 7, loc = lin >> 3;
  int mloc = loc & 3, nloc = loc >> 2;          // stripe height 4 (32 Mtiles / 8 XCDs)
  int m0 = (xcd*4 + mloc) * 128, n0 = nloc * 64;
  int tid = threadIdx.x;
  int w = tid >> 6, l = tid & 63;
  int wr = w >> 1, wc = w & 1;
  int c = l & 15, g = l >> 4;
  f32x4 acc[4][2] = {};
  int r8 = l >> 3;                  // row within the 8-row group = (row & 7)
  int sslot = (l & 7) ^ r8;         // swizzled 16B-slot index in the source row
  const u16* Ag = A + (size_t)(m0 + w*32 + r8)*K + sslot*8;   // 4 loads: rows w*32+i*8
  const u16* Wg = W + (size_t)(n0 + w*16 + r8)*K + sslot*8;   // 2 loads: rows w*16+i*8

#define STAGE(dA, dB, k0) do {                                                          \
  _Pragma("unroll")                                                                     \
  for (int i = 0; i < 4; i++)                                                           \
    __builtin_amdgcn_global_load_lds(                                                   \
        (const __attribute__((address_space(1))) void*)(Ag + (size_t)(i*8)*K + (k0)),   \
        (__attribute__((address_space(3))) void*)(dA + (w*32 + i*8)*64), 16, 0, 0);     \
  _Pragma("unroll")                                                                     \
  for (int i = 0; i < 2; i++)                                                           \
    __builtin_amdgcn_global_load_lds(                                                   \
        (const __attribute__((address_space(1))) void*)(Wg + (size_t)(i*8)*K + (k0)),   \
        (__attribute__((address_space(3))) void*)(dB + (w*16 + i*8)*64), 16, 0, 0);     \
  } while (0)

#define COMPUTE(sA, sB) do {                                                            \
  _Pragma("unroll")                                                                     \
  for (int ks = 0; ks < 2; ks++) {                                                      \
    s16x8 af[4], bq[2];                                                                 \
    int sl = ((ks*4 + g) ^ (c & 7)) * 8;                                                \
    _Pragma("unroll")                                                                   \
    for (int mt = 0; mt < 4; mt++)                                                      \
      af[mt] = *(const s16x8*)(sA + (wr*64 + mt*16 + c)*64 + sl);                       \
    _Pragma("unroll")                                                                   \
    for (int nt = 0; nt < 2; nt++)                                                      \
      bq[nt] = *(const s16x8*)(sB + (wc*32 + nt*16 + c)*64 + sl);                       \
    _Pragma("unroll")                                                                   \
    for (int mt = 0; mt < 4; mt++)                                                      \
      _Pragma("unroll")                                                                 \
      for (int nt = 0; nt < 2; nt++)                                                    \
        acc[mt][nt] = __builtin_amdgcn_mfma_f32_16x16x32_bf16(af[mt], bq[nt],           \
                                                              acc[mt][nt], 0, 0, 0);    \
  } } while (0)

  const int NT = K >> 6;            // 24 K-tiles of 64 (divisible by 3)
  STAGE(As0, Bs0, 0);
  STAGE(As1, Bs1, 64);
  STAGE(As2, Bs2, 128);
  WAITBAR(12);                      // tile0 landed; tiles 1,2 in flight
  for (int t = 0; t + 3 < NT; t += 3) {
    COMPUTE(As0, Bs0);              // tile t (landed)
    RAWBAR();                       // all waves done reading buf0
    STAGE(As0, Bs0, (t+3)*64);
    WAITBAR(12);                    // tile t+1 landed; t+2, t+3 in flight
    COMPUTE(As1, Bs1);              // tile t+1
    RAWBAR();
    STAGE(As1, Bs1, (t+4)*64);
    WAITBAR(12);                    // tile t+2 landed; t+3, t+4 in flight
    COMPUTE(As2, Bs2);              // tile t+2
    RAWBAR();
    STAGE(As2, Bs2, (t+5)*64);
    WAITBAR(12);                    // tile t+3 landed; t+4, t+5 in flight
  }
  // exit with t = NT-3: tile NT-3 landed, NT-2 and NT-1 in flight
  COMPUTE(As0, Bs0);                // tile NT-3
  WAITBAR(6);                       // tile NT-2 landed
  COMPUTE(As1, Bs1);                // tile NT-2
  WAITBAR(0);                       // tile NT-1 landed
  COMPUTE(As2, Bs2);                // tile NT-1
#undef STAGE
#undef COMPUTE

#pragma unroll
  for (int mt = 0; mt < 4; mt++)
#pragma unroll
    for (int nt = 0; nt < 2; nt++) {
      if (MODE == 1) {
#pragma unroll
        for (int r = 0; r < 4; r++) {
          int m = m0 + wr*64 + mt*16 + g*4 + r;
          int n = n0 + wc*32 + nt*16 + c;
          size_t off = (size_t)m*N + n;
          ((float*)Cv)[off] = acc[mt][nt][r] + resid[off];
        }
      } else {
        int n = n0 + wc*32 + nt*16 + c;
        int d = n & 63;
        // partner value for the RoPE pair lives in lane l^1 (adjacent column)
        f32x4 px;
#pragma unroll
        for (int r = 0; r < 4; r++) px[r] = __shfl_xor(acc[mt][nt][r], 1);
        if (n < NQ_*HD) {                          // ---- Q: rope + scatter
          int h = n >> 6;
#pragma unroll
          for (int r = 0; r < 4; r++) {
            int m = m0 + wr*64 + mt*16 + g*4 + r;
            int s = m & (S_-1), bb = m >> 11;
            float2 t2 = tab[s*32 + (d >> 1)];
            float y = (n & 1) ? acc[mt][nt][r]*t2.x + px[r]*t2.y
                              : acc[mt][nt][r]*t2.x - px[r]*t2.y;
            qp[(((size_t)(bb*NQ_ + h))*S_ + s)*64 + d] = f2bf(y);
          }
        } else if (n < (NQ_+NKV_)*HD) {            // ---- K: rope + scatter
          int hk = (n >> 6) - NQ_;
#pragma unroll
          for (int r = 0; r < 4; r++) {
            int m = m0 + wr*64 + mt*16 + g*4 + r;
            int s = m & (S_-1), bb = m >> 11;
            float2 t2 = tab[s*32 + (d >> 1)];
            float y = (n & 1) ? acc[mt][nt][r]*t2.x + px[r]*t2.y
                              : acc[mt][nt][r]*t2.x - px[r]*t2.y;
            kp[(((size_t)(bb*NKV_ + hk))*S_ + s)*64 + d] = f2bf(y);
          }
        } else {                                   // ---- V: transpose store (free)
          int hk = (n >> 6) - (NQ_+NKV_);
          int m = m0 + wr*64 + mt*16 + g*4;        // 4 consecutive tokens
          int s = m & (S_-1), bb = m >> 11;
          *(unsigned long long*)(vp + (((size_t)(bb*NKV_ + hk))*64 + d)*S_ + s) =
              pk4bf(acc[mt][nt][0], acc[mt][nt][1], acc[mt][nt][2], acc[mt][nt][3]);
        }
      }
    }
}

// ---------------- Flash attention, one wave per (b,h,32-query tile) ----------------
// R4-exact structure (proven 43.4us) + R17 defer-max (T13, verified ~ -1.4us):
// skip the alpha-exp and o/l rescale when no query's max grew by >8.
__global__ __launch_bounds__(64, 3) void k_attn(const u16* __restrict__ q,
                                                const u16* __restrict__ k,
                                                const u16* __restrict__ vt,
                                                u16* __restrict__ ao,
                                                const int* __restrict__ spp) {
  __shared__ __align__(16) u16 Pt[32*72];
  int lin = blockIdx.x;
  int xcd = lin & 7, loc = lin >> 3;
  int qb = loc & 63;
  int bh = xcd * 6 + (loc >> 6);   // [0,48)
  int h = bh % NQ_;
  int b = bh / NQ_;
  int q0 = qb * 32;
  int hk = h / (NQ_/NKV_);
  int l = threadIdx.x;
  int c = l & 15, g = l >> 4;
  int sp = spp[0];
  const u16* qptr = q + ((size_t)(b*NQ_ + h))*S_*64;
  const u16* kptr = k + ((size_t)(b*NKV_ + hk))*S_*64;
  const u16* vptr = vt + ((size_t)(b*NKV_ + hk))*64*S_;

  s16x8 qf[2][2];
#pragma unroll
  for (int qt = 0; qt < 2; qt++)
#pragma unroll
    for (int ks = 0; ks < 2; ks++)
      qf[qt][ks] = *(const s16x8*)(qptr + (size_t)(q0 + qt*16 + c)*64 + ks*32 + g*8);

  f32x4 o[4][2] = {};          // o[dt][qt]: O^T accum, row=d col=q
  float m_run[2], l_run[2];
#pragma unroll
  for (int i = 0; i < 2; i++) { m_run[i] = -1e30f; l_run[i] = 0.f; }

  int lo = sp + q0 - 256; if (lo < 0) lo = 0;
  int hi = sp + q0 + 31;  if (hi > S_ - 1) hi = S_ - 1;
  int kt0 = lo >> 6, kt1 = hi >> 6;

  s16x8 kf[4][2];
#pragma unroll
  for (int km = 0; km < 4; km++)
#pragma unroll
    for (int ks = 0; ks < 2; ks++)
      kf[km][ks] = *(const s16x8*)(kptr + (size_t)(kt0*64 + km*16 + c)*64 + ks*32 + g*8);

  for (int kt = kt0; kt <= kt1; kt++) {
    s16x8 vf[2][4];
#pragma unroll
    for (int ks = 0; ks < 2; ks++)
#pragma unroll
      for (int dt = 0; dt < 4; dt++)
        vf[ks][dt] = *(const s16x8*)(vptr + (size_t)(dt*16 + c)*S_ + kt*64 + ks*32 + g*8);

    bool full = (kt*64 + 63 <= sp + q0) && (kt*64 >= sp + q0 - 225);
#pragma unroll
    for (int qt = 0; qt < 2; qt++) {
      f32x4 sa[4];               // S^T slice for this qt: row=key col=query
      __builtin_amdgcn_s_setprio(1);
#pragma unroll
      for (int km = 0; km < 4; km++) {
        f32x4 z = {};
        z = __builtin_amdgcn_mfma_f32_16x16x32_bf16(kf[km][0], qf[qt][0], z, 0, 0, 0);
        sa[km] = __builtin_amdgcn_mfma_f32_16x16x32_bf16(kf[km][1], qf[qt][1], z, 0, 0, 0);
      }
      __builtin_amdgcn_s_setprio(0);
      if (qt == 1 && kt < kt1) {
#pragma unroll
        for (int km = 0; km < 4; km++)
#pragma unroll
          for (int ks = 0; ks < 2; ks++)
            kf[km][ks] = *(const s16x8*)(kptr + (size_t)((kt+1)*64 + km*16 + c)*64 + ks*32 + g*8);
      }
      float mx = -1e30f;
      if (full) {
#pragma unroll
        for (int km = 0; km < 4; km++)
#pragma unroll
          for (int r = 0; r < 4; r++) {
            float sv = sa[km][r] * 0.125f;
            sa[km][r] = sv;
            mx = fmaxf(mx, sv);
          }
      } else {
        int pos = sp + q0 + qt*16 + c;
#pragma unroll
        for (int km = 0; km < 4; km++)
#pragma unroll
          for (int r = 0; r < 4; r++) {
            int key = kt*64 + km*16 + g*4 + r;
            float sv = sa[km][r] * 0.125f;
            sv = ((unsigned)(pos - key) <= 256u) ? sv : -1e30f;
            sa[km][r] = sv;
            mx = fmaxf(mx, sv);
          }
      }
      mx = fmaxf(mx, __shfl_xor(mx, 16));
      mx = fmaxf(mx, __shfl_xor(mx, 32));
      // T13 defer-max: only rescale when some query's max grew by >8.
      if (__ballot(mx > m_run[qt] + 8.f) != 0) {
        float mnew = fmaxf(m_run[qt], mx);
        float alpha = __expf(m_run[qt] - mnew);
        m_run[qt] = mnew;
        l_run[qt] *= alpha;
#pragma unroll
        for (int dt = 0; dt < 4; dt++) {
          o[dt][qt][0] *= alpha; o[dt][qt][1] *= alpha;
          o[dt][qt][2] *= alpha; o[dt][qt][3] *= alpha;
        }
      }
      float mref = m_run[qt];
      float rsum = 0.f;
#pragma unroll
      for (int km = 0; km < 4; km++) {
        float p0 = __expf(sa[km][0] - mref);   // masked -1e30 underflows to 0
        float p1 = __expf(sa[km][1] - mref);
        float p2 = __expf(sa[km][2] - mref);
        float p3 = __expf(sa[km][3] - mref);
        rsum += p0 + p1 + p2 + p3;
        *(unsigned long long*)(Pt + (qt*16 + c)*72 + km*16 + g*4) = pk4bf(p0, p1, p2, p3);
      }
      rsum += __shfl_xor(rsum, 16);
      rsum += __shfl_xor(rsum, 32);
      l_run[qt] += rsum;
    }
    LDS_FENCE();   // Pt writes ordered before reads (in-order DS pipe, same wave)
    // PV: O^T += V^T @ P^T
    __builtin_amdgcn_s_setprio(1);
#pragma unroll
    for (int ks = 0; ks < 2; ks++)
#pragma unroll
      for (int qt = 0; qt < 2; qt++) {
        s16x8 pf = *(const s16x8*)(Pt + (qt*16 + c)*72 + ks*32 + g*8);
#pragma unroll
        for (int dt = 0; dt < 4; dt++)
          o[dt][qt] = __builtin_amdgcn_mfma_f32_16x16x32_bf16(vf[ks][dt], pf, o[dt][qt], 0, 0, 0);
      }
    __builtin_amdgcn_s_setprio(0);
    LDS_FENCE();   // Pt reads ordered before next iteration's writes
  }
#pragma unroll
  for (int qt = 0; qt < 2; qt++) {
    float inv = 1.f / l_run[qt];
    int qi = q0 + qt*16 + c;
    u16* row = ao + ((size_t)(b*S_) + qi)*HID + h*64;
#pragma unroll
    for (int dt = 0; dt < 4; dt++)
      *(unsigned long long*)(row + dt*16 + g*4) =
          pk4bf(o[dt][qt][0]*inv, o[dt][qt][1]*inv, o[dt][qt][2]*inv, o[dt][qt][3]*inv);
  }
}

extern "C" void kernel_launch(void* const* d_in, const int* in_sizes, int n_in,
                              void* d_out, int out_size, void* d_ws, size_t ws_size,
                              hipStream_t stream) {
  const float* x_f32    = (const float*)d_in[0];
  const float* g_f32    = (const float*)d_in[1];
  const float* wqkv_f32 = (const float*)d_in[2];
  const float* wout_f32 = (const float*)d_in[3];
  const int*   spp      = (const int*)d_in[4];
  char* ws = (char*)d_ws;
  // workspace layout (bytes)
  u16* wqkvb = (u16*)(ws);                    //  6,291,456
  u16* woutb = (u16*)(ws + 6291456);          //  4,718,592 (contiguous with wqkvb)
  u16* xn    = (u16*)(ws + 11010048);         // 12,582,912
  u16* qbuf  = (u16*)(ws + 40370176);         // 12,582,912
  u16* kbuf  = (u16*)(ws + 52953088);         //  2,097,152
  u16* vtb   = (u16*)(ws + 55050240);         //  2,097,152  (end 57,147,392)
  u16* attn  = xn;                            // aliases xn (dead after GEMM1)
  // RoPE table lives in d_out's buffer (512KB of 25MB); read only by GEMM1's
  // epilogue, which completes before GEMM2 overwrites d_out (stream-ordered).
  float2* tab = (float2*)d_out;

  k_setup<<<SETUP_BLKS, 256, 0, stream>>>(x_f32, g_f32, wqkv_f32, wout_f32,
                                          wqkvb, xn, tab, spp);
  k_gemm_bt<0><<<32*(QKVN/64), 256, 0, stream>>>(xn, wqkvb, nullptr, nullptr,
                                                 (const float2*)tab, qbuf, kbuf, vtb,
                                                 QKVN, HID);
  k_attn<<<B_*NQ_*(S_/32), 64, 0, stream>>>(qbuf, kbuf, vtb, attn, spp);
  k_gemm_bt<1><<<32*(HID/64), 256, 0, stream>>>(attn, woutb, d_out, x_f32,
                                                nullptr, nullptr, nullptr, nullptr,
                                                HID, HID);
}